// Round 10
// baseline (189.285 us; speedup 1.0000x reference)
//
#include <hip/hip_runtime.h>
#include <math.h>

#define F 128
#define OUT 128

typedef unsigned short ushort_t;
typedef __attribute__((ext_vector_type(8))) short bfrag;   // 8 bf16
typedef __attribute__((ext_vector_type(4))) float ffrag;   // 4 fp32 acc

union BU { unsigned u[4]; bfrag b; };

__device__ __forceinline__ float bf_lo(unsigned int u) {
    return __uint_as_float(u << 16);
}
__device__ __forceinline__ float bf_hi(unsigned int u) {
    return __uint_as_float(u & 0xffff0000u);
}
__device__ __forceinline__ ushort_t f2bf(float f) {
    unsigned int x = __float_as_uint(f);
    unsigned int r = x + 0x7fffu + ((x >> 16) & 1u);
    return (ushort_t)(r >> 16);
}
__device__ __forceinline__ unsigned pk2(float lo, float hi) {
    return (unsigned)f2bf(lo) | ((unsigned)f2bf(hi) << 16);
}

// ---------------------------------------------------------------------------
// K1: heterogeneous grid.
//  blocks [0,nproj): proj GEMM. Reads feat fp32, stages bf16 to LDS (As) and
//   writes abig[:, :128]. B-frags hoisted from fp32 w1 before the K-loop.
//   Epilogue (through per-wave LDS patch Ep):
//     waves 0,1 (cols 0..127):  e_dst = bf16(exp(2*(c + b1)))   uint4 stores
//     waves 2,3 (cols 128..255): srcpack chunk c = [es(4 bf16)|ft(4 bf16)],
//       es from Ep, ft from As -> ONE contiguous uint4 store per chunk.
//  blocks [nproj, nproj+nrp): rowptr (dst sorted).
// ---------------------------------------------------------------------------
#define PST 136
__global__ __launch_bounds__(256) void k1_kernel(
    const float* __restrict__ feat, const float* __restrict__ w1,
    const float* __restrict__ b1, const int* __restrict__ dst,
    int* __restrict__ row_ptr, ushort_t* __restrict__ e_dst,
    ushort_t* __restrict__ srcpack, ushort_t* __restrict__ abig,
    int n, int e, int nproj)
{
    if ((int)blockIdx.x >= nproj) {
        int i = ((int)blockIdx.x - nproj) * 256 + threadIdx.x;
        if (i >= e) return;
        int d = dst[i];
        int prev = (i == 0) ? -1 : dst[i - 1];
        for (int v = prev + 1; v <= d; ++v) row_ptr[v] = i;
        if (i == e - 1) {
            for (int v = d + 1; v <= n; ++v) row_ptr[v] = e;
        }
        return;
    }

    __shared__ ushort_t As[64 * PST];        // 17408 B  (feat bf16 tile)
    __shared__ ushort_t Ep[4][16 * 80];      // 10240 B  (epilogue patches)
    const int t = threadIdx.x;
    const int wv = t >> 6, lane = t & 63;
    const int lm = lane & 15, quad = lane >> 4;
    const int row0 = blockIdx.x * 64, col0 = wv * 64;

    // ---- staging: thread t -> row r = t>>2, feats 32q..32q+31 (q = t&3) ----
    {
        const int r = t >> 2, q = t & 3;
        const int row = row0 + r;
        unsigned up[16];
        if (row < n) {
            const float* fp = feat + (size_t)row * F + 32 * q;
#pragma unroll
            for (int i4 = 0; i4 < 8; ++i4) {
                float4 a = *(const float4*)(fp + 4 * i4);
                up[2 * i4]     = pk2(a.x, a.y);
                up[2 * i4 + 1] = pk2(a.z, a.w);
            }
        } else {
#pragma unroll
            for (int i2 = 0; i2 < 16; ++i2) up[i2] = 0;
        }
#pragma unroll
        for (int i4 = 0; i4 < 4; ++i4)
            *(uint4*)(As + r * PST + 32 * q + 8 * i4) =
                make_uint4(up[4 * i4], up[4 * i4 + 1], up[4 * i4 + 2], up[4 * i4 + 3]);
        if (row < n) {
#pragma unroll
            for (int i4 = 0; i4 < 4; ++i4)
                *(uint4*)(abig + (size_t)row * 256 + 32 * q + 8 * i4) =
                    make_uint4(up[4 * i4], up[4 * i4 + 1], up[4 * i4 + 2], up[4 * i4 + 3]);
        }
    }

    // ---- hoist B-fragments from fp32 w1 (done once, overlaps staging) ----
    bfrag bfr[4][4];
#pragma unroll
    for (int ks = 0; ks < 4; ++ks)
#pragma unroll
        for (int ni = 0; ni < 4; ++ni) {
            const int jj = col0 + ni * 16 + lm;
            const float* wcol = (jj < F) ? (w1 + jj)
                                         : (w1 + (size_t)F * F + (jj - F));
            const int k0 = ks * 32 + quad * 8;
            BU bu;
#pragma unroll
            for (int l = 0; l < 4; ++l) {
                float x0 = wcol[(size_t)(k0 + 2 * l) * F];
                float x1 = wcol[(size_t)(k0 + 2 * l + 1) * F];
                bu.u[l] = pk2(x0, x1);
            }
            bfr[ks][ni] = bu.b;
        }
    __syncthreads();

    ffrag acc[4][4];
#pragma unroll
    for (int mi = 0; mi < 4; ++mi)
#pragma unroll
        for (int ni = 0; ni < 4; ++ni) acc[mi][ni] = (ffrag){0.f, 0.f, 0.f, 0.f};

#pragma unroll
    for (int ks = 0; ks < 4; ++ks)
#pragma unroll
        for (int mi = 0; mi < 4; ++mi) {
            bfrag af = *(const bfrag*)(As + (mi * 16 + lm) * PST + ks * 32 + quad * 8);
#pragma unroll
            for (int ni = 0; ni < 4; ++ni)
                acc[mi][ni] = __builtin_amdgcn_mfma_f32_16x16x32_bf16(
                    af, bfr[ks][ni], acc[mi][ni], 0, 0, 0);
        }

    float bias[4];
#pragma unroll
    for (int ni = 0; ni < 4; ++ni)
        bias[ni] = (col0 < F) ? b1[col0 + ni * 16 + lm] : 0.f;

#pragma unroll
    for (int mi = 0; mi < 4; ++mi) {
        // compute-layout write into per-wave patch
#pragma unroll
        for (int ni = 0; ni < 4; ++ni)
#pragma unroll
            for (int r = 0; r < 4; ++r)
                Ep[wv][(quad * 4 + r) * 80 + ni * 16 + lm] =
                    f2bf(__expf(2.f * (acc[mi][ni][r] + bias[ni])));

        if (col0 < F) {
            // e_dst: 2 passes x (8 rows x 8 lanes x 16B), coalesced
#pragma unroll
            for (int ps = 0; ps < 2; ++ps) {
                int rl = ps * 8 + (lane >> 3), co = (lane & 7) * 8;
                uint4 vv = *(const uint4*)(&Ep[wv][rl * 80 + co]);
                int grow = row0 + mi * 16 + rl;
                if (grow < n)
                    *(uint4*)(e_dst + (size_t)grow * F + col0 + co) = vv;
            }
        } else {
            // srcpack: 4 passes x (4 rows x 16 chunks); chunk = [es 8B | ft 8B]
            const int cbase = (col0 - F) >> 2;       // 16*(wv-2)
#pragma unroll
            for (int ps = 0; ps < 4; ++ps) {
                int rl = ps * 4 + (lane >> 4);       // row in patch 0..15
                int c  = lane & 15;                  // chunk within wave
                int cg = cbase + c;                  // global chunk 0..31
                uint2 es = *(const uint2*)(&Ep[wv][rl * 80 + c * 4]);
                uint2 ft = *(const uint2*)(As + (mi * 16 + rl) * PST + cg * 4);
                int grow = row0 + mi * 16 + rl;
                if (grow < n)
                    *(uint4*)(srcpack + (size_t)grow * 256 + cg * 8) =
                        make_uint4(es.x, es.y, ft.x, ft.y);
            }
        }
    }
}

// ---------------------------------------------------------------------------
// K2: fused score+softmax+aggregate (unchanged). One 32-lane half-wave per
// node; one uint4 gather per edge gives 4 e_src + 4 feat bf16 per lane.
// Static softmax bound M = b2 + sum|w2|; 4-edge ILP.
// Writes neigh bf16 to abig[:, 128:].
// ---------------------------------------------------------------------------
__global__ __launch_bounds__(256) void fused_kernel(
    const ushort_t* __restrict__ e_dst, const ushort_t* __restrict__ srcpack,
    const int* __restrict__ src, const int* __restrict__ row_ptr,
    const float* __restrict__ w2, ushort_t* __restrict__ abig, int n)
{
    const int v = (int)((blockIdx.x * 256u + threadIdx.x) >> 5);
    const int fl = threadIdx.x & 31;
    const int sbase = threadIdx.x & 32;

    const float4 wv4 = ((const float4*)w2)[fl];
    const float w0 = wv4.x, w1_ = wv4.y, w2_ = wv4.z, w3_ = wv4.w;
    float sw = w0 + w1_ + w2_ + w3_;
    float aw = fabsf(w0) + fabsf(w1_) + fabsf(w2_) + fabsf(w3_);
#pragma unroll
    for (int off = 16; off; off >>= 1) {
        sw += __shfl_xor(sw, off, 64);
        aw += __shfl_xor(aw, off, 64);
    }
    const float K = sw - aw;           // score - M = K - 2*pv  (always <= 0)

    if (v >= n) return;
    const int begin = row_ptr[v], end = row_ptr[v + 1];

    const uint2 ud = *(const uint2*)(e_dst + (size_t)v * F + fl * 4);
    const float ea0 = bf_lo(ud.x), ea1 = bf_hi(ud.x);
    const float ea2 = bf_lo(ud.y), ea3 = bf_hi(ud.y);

    float s = 0.f, a0 = 0.f, a1 = 0.f, a2 = 0.f, a3 = 0.f;

    for (int cb = begin; cb < end; cb += 32) {
        const int clen = min(32, end - cb);
        const int sv = (fl < clen) ? src[cb + fl] : 0;
        int jj = 0;
        for (; jj + 4 <= clen; jj += 4) {
            uint4 u[4];
#pragma unroll
            for (int q = 0; q < 4; ++q) {
                const int sq = __shfl(sv, sbase + jj + q, 64);
                u[q] = ((const uint4*)(srcpack + (size_t)sq * 256))[fl];
            }
            float p[4];
#pragma unroll
            for (int q = 0; q < 4; ++q) {
                float r;
                r = __builtin_amdgcn_rcpf(fmaf(ea0, bf_lo(u[q].x), 1.f)); p[q] = w0 * r;
                r = __builtin_amdgcn_rcpf(fmaf(ea1, bf_hi(u[q].x), 1.f)); p[q] = fmaf(w1_, r, p[q]);
                r = __builtin_amdgcn_rcpf(fmaf(ea2, bf_lo(u[q].y), 1.f)); p[q] = fmaf(w2_, r, p[q]);
                r = __builtin_amdgcn_rcpf(fmaf(ea3, bf_hi(u[q].y), 1.f)); p[q] = fmaf(w3_, r, p[q]);
            }
#pragma unroll
            for (int off = 16; off; off >>= 1) {
#pragma unroll
                for (int q = 0; q < 4; ++q) p[q] += __shfl_xor(p[q], off, 64);
            }
            float g[4];
#pragma unroll
            for (int q = 0; q < 4; ++q) g[q] = __expf(fmaf(-2.f, p[q], K));
            s += (g[0] + g[1]) + (g[2] + g[3]);
#pragma unroll
            for (int q = 0; q < 4; ++q) {
                a0 = fmaf(g[q], bf_lo(u[q].z), a0);
                a1 = fmaf(g[q], bf_hi(u[q].z), a1);
                a2 = fmaf(g[q], bf_lo(u[q].w), a2);
                a3 = fmaf(g[q], bf_hi(u[q].w), a3);
            }
        }
        for (; jj < clen; ++jj) {
            const int s0 = __shfl(sv, sbase + jj, 64);
            const uint4 u0 = ((const uint4*)(srcpack + (size_t)s0 * 256))[fl];
            float r, p0;
            r = __builtin_amdgcn_rcpf(fmaf(ea0, bf_lo(u0.x), 1.f)); p0 = w0 * r;
            r = __builtin_amdgcn_rcpf(fmaf(ea1, bf_hi(u0.x), 1.f)); p0 = fmaf(w1_, r, p0);
            r = __builtin_amdgcn_rcpf(fmaf(ea2, bf_lo(u0.y), 1.f)); p0 = fmaf(w2_, r, p0);
            r = __builtin_amdgcn_rcpf(fmaf(ea3, bf_hi(u0.y), 1.f)); p0 = fmaf(w3_, r, p0);
#pragma unroll
            for (int off = 16; off; off >>= 1) p0 += __shfl_xor(p0, off, 64);
            const float g0 = __expf(fmaf(-2.f, p0, K));
            s += g0;
            a0 = fmaf(g0, bf_lo(u0.z), a0);
            a1 = fmaf(g0, bf_hi(u0.z), a1);
            a2 = fmaf(g0, bf_lo(u0.w), a2);
            a3 = fmaf(g0, bf_hi(u0.w), a3);
        }
    }

    const float inv = (end > begin) ? 1.f / s : 0.f;
    ushort4 o = make_ushort4(f2bf(a0 * inv), f2bf(a1 * inv),
                             f2bf(a2 * inv), f2bf(a3 * inv));
    *(ushort4*)(abig + (size_t)v * 256 + 128 + fl * 4) = o;
}

// ---------------------------------------------------------------------------
// K3: out[n x 128] = abig(bf16, K=256) @ wf + bf.  B-frags hoisted from fp32
// wf (L2-hot) before the K-loop; fp32 output stores naturally coalesced.
// Block = 64 rows x 128 cols, 4 waves (wave w: cols 32w..32w+31).
// ---------------------------------------------------------------------------
#define OST 280
__global__ __launch_bounds__(256) void out_gemm_kernel(
    const ushort_t* __restrict__ abig, const float* __restrict__ wf,
    const float* __restrict__ bfv, float* __restrict__ out, int n)
{
    __shared__ ushort_t As[64 * OST];        // 35840 B
    const int t = threadIdx.x;
    const int wv = t >> 6, lane = t & 63;
    const int lm = lane & 15, quad = lane >> 4;
    const int row0 = blockIdx.x * 64, col0 = wv * 32;

#pragma unroll
    for (int k = 0; k < 8; ++k) {            // 64 rows x 32 uint4, coalesced
        int l = k * 256 + t;
        int r = l >> 5, ch = l & 31;
        uint4 d = make_uint4(0, 0, 0, 0);
        if (row0 + r < n) d = *(const uint4*)(abig + (size_t)(row0 + r) * 256 + ch * 8);
        *(uint4*)(As + r * OST + ch * 8) = d;
    }

    bfrag bfr[8][2];
#pragma unroll
    for (int ks = 0; ks < 8; ++ks)
#pragma unroll
        for (int ni = 0; ni < 2; ++ni) {
            const int jj = col0 + ni * 16 + lm;
            const int k0 = ks * 32 + quad * 8;
            BU bu;
#pragma unroll
            for (int l = 0; l < 4; ++l) {
                float x0 = wf[(size_t)(k0 + 2 * l) * F + jj];
                float x1 = wf[(size_t)(k0 + 2 * l + 1) * F + jj];
                bu.u[l] = pk2(x0, x1);
            }
            bfr[ks][ni] = bu.b;
        }
    __syncthreads();

    ffrag acc[4][2];
#pragma unroll
    for (int mi = 0; mi < 4; ++mi)
#pragma unroll
        for (int ni = 0; ni < 2; ++ni) acc[mi][ni] = (ffrag){0.f, 0.f, 0.f, 0.f};

#pragma unroll
    for (int ks = 0; ks < 8; ++ks)
#pragma unroll
        for (int mi = 0; mi < 4; ++mi) {
            bfrag af = *(const bfrag*)(As + (mi * 16 + lm) * OST + ks * 32 + quad * 8);
#pragma unroll
            for (int ni = 0; ni < 2; ++ni)
                acc[mi][ni] = __builtin_amdgcn_mfma_f32_16x16x32_bf16(
                    af, bfr[ks][ni], acc[mi][ni], 0, 0, 0);
        }

#pragma unroll
    for (int ni = 0; ni < 2; ++ni) {
        const int j = col0 + ni * 16 + lm;
        const float bb = bfv[j];
#pragma unroll
        for (int mi = 0; mi < 4; ++mi)
#pragma unroll
            for (int r = 0; r < 4; ++r) {
                int grow = row0 + mi * 16 + quad * 4 + r;
                if (grow < n) out[(size_t)grow * OUT + j] = acc[mi][ni][r] + bb;
            }
    }
}

// ---------------------------------------------------------------------------
extern "C" void kernel_launch(void* const* d_in, const int* in_sizes, int n_in,
                              void* d_out, int out_size, void* d_ws, size_t ws_size,
                              hipStream_t stream)
{
    const float* feat = (const float*)d_in[0];
    const int*   src  = (const int*)d_in[1];
    const int*   dst  = (const int*)d_in[2];
    const float* w1   = (const float*)d_in[3];
    const float* b1   = (const float*)d_in[4];
    const float* w2   = (const float*)d_in[5];
    const float* b2   = (const float*)d_in[6];  (void)b2; // cancels in softmax
    const float* wf   = (const float*)d_in[7];
    const float* bfv  = (const float*)d_in[8];
    float* out = (float*)d_out;

    const int n = in_sizes[0] / F;   // 40000
    const int e = in_sizes[1];       // 640000

    ushort_t* abig    = (ushort_t*)d_ws;                   // n*256 bf16 [feat|neigh]
    ushort_t* e_dst   = abig + (size_t)n * 256;            // n*128 bf16
    ushort_t* srcpack = e_dst + (size_t)n * 128;           // n*256 bf16 interleaved
    int* row_ptr      = (int*)(srcpack + (size_t)n * 256); // n+1

    const int nproj = (n + 63) / 64;        // 625
    const int nrp   = (e + 255) / 256;      // 2500

    k1_kernel<<<nproj + nrp, 256, 0, stream>>>(
        feat, w1, b1, dst, row_ptr, e_dst, srcpack, abig, n, e, nproj);
    fused_kernel<<<(n + 7) / 8, 256, 0, stream>>>(
        e_dst, srcpack, src, row_ptr, w2, abig, n);
    out_gemm_kernel<<<(n + 63) / 64, 256, 0, stream>>>(abig, wf, bfv, out, n);
}

// Round 11
// 180.945 us; speedup vs baseline: 1.0461x; 1.0461x over previous
//
#include <hip/hip_runtime.h>
#include <math.h>

#define F 128
#define OUT 128

typedef unsigned short ushort_t;
typedef __attribute__((ext_vector_type(8))) short bfrag;   // 8 bf16
typedef __attribute__((ext_vector_type(4))) float ffrag;   // 4 fp32 acc

__device__ __forceinline__ float bf_lo(unsigned int u) {
    return __uint_as_float(u << 16);
}
__device__ __forceinline__ float bf_hi(unsigned int u) {
    return __uint_as_float(u & 0xffff0000u);
}
__device__ __forceinline__ ushort_t f2bf(float f) {
    unsigned int x = __float_as_uint(f);
    unsigned int r = x + 0x7fffu + ((x >> 16) & 1u);
    return (ushort_t)(r >> 16);
}
__device__ __forceinline__ unsigned pk2(float lo, float hi) {
    return (unsigned)f2bf(lo) | ((unsigned)f2bf(hi) << 16);
}

// ---------------------------------------------------------------------------
// prep: heterogeneous grid.
//  part0: feat fp32 -> abig[:, :128] bf16 (vector stores only).
//  part1: btp[j*128+k] = bf16(B[k][j]), B = [w1[:F] | w1[F:]], j=0..255.
//  part2: btf[j*256+k] = bf16(wf[k][j]), j=0..127.
//  part3: rowptr (dst sorted).
// ---------------------------------------------------------------------------
__global__ __launch_bounds__(256) void prep_kernel(
    const float* __restrict__ feat, const float* __restrict__ w1,
    const float* __restrict__ wf, const int* __restrict__ dst,
    ushort_t* __restrict__ abig, ushort_t* __restrict__ btp,
    ushort_t* __restrict__ btf, int* __restrict__ row_ptr,
    int n, int e, int nb0, int nb1, int nb2)
{
    const int b = blockIdx.x, t = threadIdx.x;
    if (b < nb0) {
        int i = b * 256 + t;
        if (i >= n * 16) return;
        int row = i >> 4, c = (i & 15) * 8;
        float4 a = *(const float4*)(feat + (size_t)row * F + c);
        float4 bb = *(const float4*)(feat + (size_t)row * F + c + 4);
        *(uint4*)(abig + (size_t)row * 256 + c) =
            make_uint4(pk2(a.x, a.y), pk2(a.z, a.w), pk2(bb.x, bb.y), pk2(bb.z, bb.w));
    } else if (b < nb0 + nb1) {
        int idx = (b - nb0) * 256 + t;                 // 0..32767
        int j = idx >> 7, k = idx & 127;
        float v = (j < F) ? w1[(size_t)k * F + j]
                          : w1[(size_t)(F + k) * F + (j - F)];
        btp[idx] = f2bf(v);
    } else if (b < nb0 + nb1 + nb2) {
        int idx = (b - nb0 - nb1) * 256 + t;           // 0..32767
        int j = idx >> 8, k = idx & 255;
        btf[idx] = f2bf(wf[(size_t)k * F + j]);
    } else {
        int i = (b - nb0 - nb1 - nb2) * 256 + t;
        if (i >= e) return;
        int d = dst[i];
        int prev = (i == 0) ? -1 : dst[i - 1];
        for (int v = prev + 1; v <= d; ++v) row_ptr[v] = i;
        if (i == e - 1) {
            for (int v = d + 1; v <= n; ++v) row_ptr[v] = e;
        }
    }
}

// ---------------------------------------------------------------------------
// G1 (proj): 16-row tiles (2500 blocks -> ~10 blocks/CU for latency hiding).
// C[16 x 256] = abig_feat(bf16) @ btp, epilogue exp(2*(c+bias)).
// 4 waves: wave w owns cols 64w..64w+63 (4 x 16-col MFMA frags, mi=1).
// Waves 0,1 -> e_dst (+b1), coalesced uint4 via Ep-LDS transpose.
// Waves 2,3 -> srcpack FULL chunks [es|ft] (es from Ep, ft from As) as uint4.
// ---------------------------------------------------------------------------
#define PST 136
__global__ __launch_bounds__(256) void proj_gemm_kernel(
    const ushort_t* __restrict__ abig, const ushort_t* __restrict__ btp,
    const float* __restrict__ b1, ushort_t* __restrict__ e_dst,
    ushort_t* __restrict__ srcpack, int n)
{
    __shared__ ushort_t As[16 * PST];        // 4352 B
    __shared__ ushort_t Ep[4][16 * 80];      // 10240 B
    const int t = threadIdx.x;
    const int wv = t >> 6, lane = t & 63;
    const int lm = lane & 15, quad = lane >> 4;
    const int row0 = blockIdx.x * 16, col0 = wv * 64;

    {   // staging: 16 rows x 16 uint4, one per thread, coalesced
        int r = t >> 4, ch = t & 15;
        uint4 d = make_uint4(0, 0, 0, 0);
        if (row0 + r < n) d = *(const uint4*)(abig + (size_t)(row0 + r) * 256 + ch * 8);
        *(uint4*)(As + r * PST + ch * 8) = d;
    }

    bfrag bfr[4][4];
#pragma unroll
    for (int ks = 0; ks < 4; ++ks)
#pragma unroll
        for (int ni = 0; ni < 4; ++ni)
            bfr[ks][ni] = *(const bfrag*)(btp + (size_t)(col0 + ni * 16 + lm) * 128
                                          + ks * 32 + quad * 8);
    __syncthreads();

    ffrag acc[4];
#pragma unroll
    for (int ni = 0; ni < 4; ++ni) acc[ni] = (ffrag){0.f, 0.f, 0.f, 0.f};

#pragma unroll
    for (int ks = 0; ks < 4; ++ks) {
        bfrag af = *(const bfrag*)(As + lm * PST + ks * 32 + quad * 8);
#pragma unroll
        for (int ni = 0; ni < 4; ++ni)
            acc[ni] = __builtin_amdgcn_mfma_f32_16x16x32_bf16(
                af, bfr[ks][ni], acc[ni], 0, 0, 0);
    }

    float bias[4];
#pragma unroll
    for (int ni = 0; ni < 4; ++ni)
        bias[ni] = (col0 < F) ? b1[col0 + ni * 16 + lm] : 0.f;

    // compute-layout write into per-wave patch (wave-local, no barrier needed)
#pragma unroll
    for (int ni = 0; ni < 4; ++ni)
#pragma unroll
        for (int r = 0; r < 4; ++r)
            Ep[wv][(quad * 4 + r) * 80 + ni * 16 + lm] =
                f2bf(__expf(2.f * (acc[ni][r] + bias[ni])));

    if (col0 < F) {
        // e_dst: 2 passes x (8 rows x 8 lanes x 16B), coalesced
#pragma unroll
        for (int ps = 0; ps < 2; ++ps) {
            int rl = ps * 8 + (lane >> 3), co = (lane & 7) * 8;
            uint4 vv = *(const uint4*)(&Ep[wv][rl * 80 + co]);
            int grow = row0 + rl;
            if (grow < n)
                *(uint4*)(e_dst + (size_t)grow * F + col0 + co) = vv;
        }
    } else {
        // srcpack: 4 passes x (4 rows x 16 chunks); chunk = [es 8B | ft 8B]
        const int cbase = (col0 - F) >> 2;       // 16*(wv-2)
#pragma unroll
        for (int ps = 0; ps < 4; ++ps) {
            int rl = ps * 4 + (lane >> 4);       // row 0..15
            int c  = lane & 15;                  // chunk within wave
            int cg = cbase + c;                  // global chunk 0..31
            uint2 es = *(const uint2*)(&Ep[wv][rl * 80 + c * 4]);
            uint2 ft = *(const uint2*)(As + rl * PST + cg * 4);
            int grow = row0 + rl;
            if (grow < n)
                *(uint4*)(srcpack + (size_t)grow * 256 + cg * 8) =
                    make_uint4(es.x, es.y, ft.x, ft.y);
        }
    }
}

// ---------------------------------------------------------------------------
// K2: fused score+softmax+aggregate (unchanged). One 32-lane half-wave per
// node; one uint4 gather per edge gives 4 e_src + 4 feat bf16 per lane.
// Static softmax bound M = b2 + sum|w2|; 4-edge ILP.
// Writes neigh bf16 to abig[:, 128:].
// ---------------------------------------------------------------------------
__global__ __launch_bounds__(256) void fused_kernel(
    const ushort_t* __restrict__ e_dst, const ushort_t* __restrict__ srcpack,
    const int* __restrict__ src, const int* __restrict__ row_ptr,
    const float* __restrict__ w2, ushort_t* __restrict__ abig, int n)
{
    const int v = (int)((blockIdx.x * 256u + threadIdx.x) >> 5);
    const int fl = threadIdx.x & 31;
    const int sbase = threadIdx.x & 32;

    const float4 wv4 = ((const float4*)w2)[fl];
    const float w0 = wv4.x, w1_ = wv4.y, w2_ = wv4.z, w3_ = wv4.w;
    float sw = w0 + w1_ + w2_ + w3_;
    float aw = fabsf(w0) + fabsf(w1_) + fabsf(w2_) + fabsf(w3_);
#pragma unroll
    for (int off = 16; off; off >>= 1) {
        sw += __shfl_xor(sw, off, 64);
        aw += __shfl_xor(aw, off, 64);
    }
    const float K = sw - aw;           // score - M = K - 2*pv  (always <= 0)

    if (v >= n) return;
    const int begin = row_ptr[v], end = row_ptr[v + 1];

    const uint2 ud = *(const uint2*)(e_dst + (size_t)v * F + fl * 4);
    const float ea0 = bf_lo(ud.x), ea1 = bf_hi(ud.x);
    const float ea2 = bf_lo(ud.y), ea3 = bf_hi(ud.y);

    float s = 0.f, a0 = 0.f, a1 = 0.f, a2 = 0.f, a3 = 0.f;

    for (int cb = begin; cb < end; cb += 32) {
        const int clen = min(32, end - cb);
        const int sv = (fl < clen) ? src[cb + fl] : 0;
        int jj = 0;
        for (; jj + 4 <= clen; jj += 4) {
            uint4 u[4];
#pragma unroll
            for (int q = 0; q < 4; ++q) {
                const int sq = __shfl(sv, sbase + jj + q, 64);
                u[q] = ((const uint4*)(srcpack + (size_t)sq * 256))[fl];
            }
            float p[4];
#pragma unroll
            for (int q = 0; q < 4; ++q) {
                float r;
                r = __builtin_amdgcn_rcpf(fmaf(ea0, bf_lo(u[q].x), 1.f)); p[q] = w0 * r;
                r = __builtin_amdgcn_rcpf(fmaf(ea1, bf_hi(u[q].x), 1.f)); p[q] = fmaf(w1_, r, p[q]);
                r = __builtin_amdgcn_rcpf(fmaf(ea2, bf_lo(u[q].y), 1.f)); p[q] = fmaf(w2_, r, p[q]);
                r = __builtin_amdgcn_rcpf(fmaf(ea3, bf_hi(u[q].y), 1.f)); p[q] = fmaf(w3_, r, p[q]);
            }
#pragma unroll
            for (int off = 16; off; off >>= 1) {
#pragma unroll
                for (int q = 0; q < 4; ++q) p[q] += __shfl_xor(p[q], off, 64);
            }
            float g[4];
#pragma unroll
            for (int q = 0; q < 4; ++q) g[q] = __expf(fmaf(-2.f, p[q], K));
            s += (g[0] + g[1]) + (g[2] + g[3]);
#pragma unroll
            for (int q = 0; q < 4; ++q) {
                a0 = fmaf(g[q], bf_lo(u[q].z), a0);
                a1 = fmaf(g[q], bf_hi(u[q].z), a1);
                a2 = fmaf(g[q], bf_lo(u[q].w), a2);
                a3 = fmaf(g[q], bf_hi(u[q].w), a3);
            }
        }
        for (; jj < clen; ++jj) {
            const int s0 = __shfl(sv, sbase + jj, 64);
            const uint4 u0 = ((const uint4*)(srcpack + (size_t)s0 * 256))[fl];
            float r, p0;
            r = __builtin_amdgcn_rcpf(fmaf(ea0, bf_lo(u0.x), 1.f)); p0 = w0 * r;
            r = __builtin_amdgcn_rcpf(fmaf(ea1, bf_hi(u0.x), 1.f)); p0 = fmaf(w1_, r, p0);
            r = __builtin_amdgcn_rcpf(fmaf(ea2, bf_lo(u0.y), 1.f)); p0 = fmaf(w2_, r, p0);
            r = __builtin_amdgcn_rcpf(fmaf(ea3, bf_hi(u0.y), 1.f)); p0 = fmaf(w3_, r, p0);
#pragma unroll
            for (int off = 16; off; off >>= 1) p0 += __shfl_xor(p0, off, 64);
            const float g0 = __expf(fmaf(-2.f, p0, K));
            s += g0;
            a0 = fmaf(g0, bf_lo(u0.z), a0);
            a1 = fmaf(g0, bf_hi(u0.z), a1);
            a2 = fmaf(g0, bf_lo(u0.w), a2);
            a3 = fmaf(g0, bf_hi(u0.w), a3);
        }
    }

    const float inv = (end > begin) ? 1.f / s : 0.f;
    ushort4 o = make_ushort4(f2bf(a0 * inv), f2bf(a1 * inv),
                             f2bf(a2 * inv), f2bf(a3 * inv));
    *(ushort4*)(abig + (size_t)v * 256 + 128 + fl * 4) = o;
}

// ---------------------------------------------------------------------------
// G2 (out): 16-row tiles (2500 blocks). out[16 x 128] = abig(bf16,K=256)@btf+bf.
// 4 waves: wave w owns cols 32w..32w+31. B-frags from pre-converted btf.
// ---------------------------------------------------------------------------
#define OST 264
__global__ __launch_bounds__(256) void out_gemm_kernel(
    const ushort_t* __restrict__ abig, const ushort_t* __restrict__ btf,
    const float* __restrict__ bfv, float* __restrict__ out, int n)
{
    __shared__ ushort_t As[16 * OST];        // 8448 B
    const int t = threadIdx.x;
    const int wv = t >> 6, lane = t & 63;
    const int lm = lane & 15, quad = lane >> 4;
    const int row0 = blockIdx.x * 16, col0 = wv * 32;

#pragma unroll
    for (int k = 0; k < 2; ++k) {            // 16 rows x 32 uint4, coalesced
        int l = k * 256 + t;
        int r = l >> 5, ch = l & 31;
        uint4 d = make_uint4(0, 0, 0, 0);
        if (row0 + r < n) d = *(const uint4*)(abig + (size_t)(row0 + r) * 256 + ch * 8);
        *(uint4*)(As + r * OST + ch * 8) = d;
    }

    bfrag bfr[8][2];
#pragma unroll
    for (int ks = 0; ks < 8; ++ks)
#pragma unroll
        for (int ni = 0; ni < 2; ++ni)
            bfr[ks][ni] = *(const bfrag*)(btf + (size_t)(col0 + ni * 16 + lm) * 256
                                          + ks * 32 + quad * 8);
    __syncthreads();

    ffrag acc[2];
#pragma unroll
    for (int ni = 0; ni < 2; ++ni) acc[ni] = (ffrag){0.f, 0.f, 0.f, 0.f};

#pragma unroll
    for (int ks = 0; ks < 8; ++ks) {
        bfrag af = *(const bfrag*)(As + lm * OST + ks * 32 + quad * 8);
#pragma unroll
        for (int ni = 0; ni < 2; ++ni)
            acc[ni] = __builtin_amdgcn_mfma_f32_16x16x32_bf16(
                af, bfr[ks][ni], acc[ni], 0, 0, 0);
    }

#pragma unroll
    for (int ni = 0; ni < 2; ++ni) {
        const int j = col0 + ni * 16 + lm;
        const float bb = bfv[j];
#pragma unroll
        for (int r = 0; r < 4; ++r) {
            int grow = row0 + quad * 4 + r;
            if (grow < n) out[(size_t)grow * OUT + j] = acc[ni][r] + bb;
        }
    }
}

// ---------------------------------------------------------------------------
extern "C" void kernel_launch(void* const* d_in, const int* in_sizes, int n_in,
                              void* d_out, int out_size, void* d_ws, size_t ws_size,
                              hipStream_t stream)
{
    const float* feat = (const float*)d_in[0];
    const int*   src  = (const int*)d_in[1];
    const int*   dst  = (const int*)d_in[2];
    const float* w1   = (const float*)d_in[3];
    const float* b1   = (const float*)d_in[4];
    const float* w2   = (const float*)d_in[5];
    const float* b2   = (const float*)d_in[6];  (void)b2; // cancels in softmax
    const float* wf   = (const float*)d_in[7];
    const float* bfv  = (const float*)d_in[8];
    float* out = (float*)d_out;

    const int n = in_sizes[0] / F;   // 40000
    const int e = in_sizes[1];       // 640000

    ushort_t* abig    = (ushort_t*)d_ws;                   // n*256 bf16 [feat|neigh]
    ushort_t* e_dst   = abig + (size_t)n * 256;            // n*128 bf16
    ushort_t* srcpack = e_dst + (size_t)n * 128;           // n*256 bf16 interleaved
    ushort_t* btp     = srcpack + (size_t)n * 256;         // 256*128 bf16 col-major
    ushort_t* btf     = btp + 32768;                       // 128*256 bf16 col-major
    int* row_ptr      = (int*)(btf + 32768);               // n+1

    const int nb0 = (n * 16 + 255) / 256;   // 2500
    const int nb1 = 128, nb2 = 128;
    const int nb3 = (e + 255) / 256;        // 2500

    prep_kernel<<<nb0 + nb1 + nb2 + nb3, 256, 0, stream>>>(
        feat, w1, wf, dst, abig, btp, btf, row_ptr, n, e, nb0, nb1, nb2);
    proj_gemm_kernel<<<(n + 15) / 16, 256, 0, stream>>>(
        abig, btp, b1, e_dst, srcpack, n);
    fused_kernel<<<(n + 7) / 8, 256, 0, stream>>>(
        e_dst, srcpack, src, row_ptr, w2, abig, n);
    out_gemm_kernel<<<(n + 15) / 16, 256, 0, stream>>>(abig, btf, bfv, out, n);
}